// Round 9
// baseline (235.782 us; speedup 1.0000x reference)
//
#include <hip/hip_runtime.h>

typedef unsigned short u16;
typedef unsigned int   u32;
typedef __attribute__((ext_vector_type(8))) short bf8_t;   // 8 x bf16 (4 VGPRs)
typedef __attribute__((ext_vector_type(4))) float f4_t;    // 4 x fp32 acc

#define NB 256
#define NS 1024

__device__ __forceinline__ u16 f2bf(float f){   // RNE (used in prep only)
    u32 u = __float_as_uint(f);
    return (u16)((u + 0x7fffu + ((u >> 16) & 1u)) >> 16);
}
// 2 x fp32 -> packed bf16 (truncate), single v_perm_b32
__device__ __forceinline__ u32 pack_trunc(float lo, float hi){
    return __builtin_amdgcn_perm(__float_as_uint(hi), __float_as_uint(lo), 0x07060302u);
}

// ---- fused prep: blocks 0..511 -> per-(b,br) WeffT fragments + Cs (+y_trans);
//                  blocks 512..519 -> W (x-transform) B-fragment layout ----
__global__ __launch_bounds__(256) void prep_kernel(
    const float* __restrict__ y,    const float* __restrict__ wty,
    const float* __restrict__ bty,  const float* __restrict__ aty,
    const float* __restrict__ uid,  const float* __restrict__ ose, const float* __restrict__ zipc,
    const float* __restrict__ wlx,  const float* __restrict__ wnx,
    const float* __restrict__ lw1,  const float* __restrict__ lb1,
    const float* __restrict__ nw1,  const float* __restrict__ nb1,
    u32* __restrict__ wtf, u32* __restrict__ weff, float* __restrict__ cs)
{
    const int tid = threadIdx.x;
    const int bx  = blockIdx.x;

    if (bx >= 512) {
        // ---- wtf part: unit u = (br*16 + n*2 + ks)*64 + lane ----
        int u = (bx - 512)*256 + tid;   // 0..2047
        int lane = u & 63, fr = u >> 6;
        int br = fr >> 4, t = fr & 15, n = t >> 1, ks = t & 1;
        int q = lane >> 4, lm = lane & 15;
        const float* W = br ? wnx : wlx;
        u32 out[4];
        #pragma unroll
        for (int p = 0; p < 4; ++p) {
            int k = ks*32 + q*8 + p*2;
            float lo = W[k*128 + n*16 + lm];
            float hi = W[(k+1)*128 + n*16 + lm];
            out[p] = (u32)f2bf(lo) | ((u32)f2bf(hi) << 16);
        }
        *(uint4*)&wtf[u*4] = make_uint4(out[0], out[1], out[2], out[3]);
        return;
    }

    __shared__ float yl[64];
    __shared__ float sq[128];
    __shared__ float yv[128];
    __shared__ float cpart[240];

    const int b  = bx >> 1;
    const int br = bx & 1;
    const float* w1 = br ? nw1 : lw1;
    const float* b1 = br ? nb1 : lb1;

    // --- y_trans for this b ---
    if (tid < 64) yl[tid] = y[b*64 + tid];
    __syncthreads();
    float v = 0.f;
    if (tid < 128) {
        float acc = bty[tid];
        for (int k = 0; k < 64; ++k) acc = fmaf(yl[k], wty[k*128 + tid], acc);
        float a = aty[0];
        v = (acc >= 0.f) ? acc : a * acc;
        sq[tid] = v * v;
    }
    __syncthreads();
    for (int s = 64; s >= 1; s >>= 1) { if (tid < s) sq[tid] += sq[tid+s]; __syncthreads(); }
    if (tid < 128) yv[tid] = v * (1.f / fmaxf(sqrtf(sq[0]), 1e-12f));
    __syncthreads();

    // --- WeffT fragments: unit = fragrow*64+lane, fragrow = h*6+nj*2+ks ---
    for (int u = tid; u < 768; u += 256) {
        int lane = u & 63, fr = u >> 6;
        int h = fr / 6, t = fr % 6, nj = t >> 1, ks = t & 1;
        int q = lane >> 4, lm = lane & 15, j = nj*16 + lm;
        u32 out[4];
        #pragma unroll
        for (int p = 0; p < 4; ++p) {
            u32 w = 0;
            #pragma unroll
            for (int e = 0; e < 2; ++e) {
                int k = ks*32 + q*8 + p*2 + e;
                float val = 0.f;
                if (j < 40)
                    val = w1[k*40 + j] + w1[(128+k)*40 + j] + yv[h*64 + k] * w1[(64+k)*40 + j];
                w |= ((u32)f2bf(val)) << (16*e);
            }
            out[p] = w;
        }
        *(uint4*)&weff[((size_t)(br*NB + b)*12 + fr)*64*4 + lane*4] =
            make_uint4(out[0], out[1], out[2], out[3]);
    }

    // --- Cs partials: 240 threads, cj = h*40+j, slice of 120 terms ---
    if (tid < 240) {
        int cj = tid / 3, sl = tid % 3;
        int h = cj / 40, j = cj % 40;
        float acc = 0.f;
        for (int t = sl*40; t < sl*40 + 40; ++t) {
            if (t < 64) {
                acc = fmaf(yv[h*64 + t], w1[(192+t)*40 + j] - w1[(128+t)*40 + j], acc);
            } else {
                int u = t - 64;
                float sv, wv;
                if (u < 32)      { sv = uid[b*32 + u];        wv = w1[(256+u)*40 + j]; }
                else if (u < 40) { sv = ose[b*8 + (u-32)];    wv = w1[(288+(u-32))*40 + j]; }
                else             { sv = zipc[b*16 + (u-40)];  wv = w1[(296+(u-40))*40 + j]; }
                acc = fmaf(sv, wv, acc);
            }
        }
        cpart[tid] = acc;
    }
    __syncthreads();
    if (tid < 96) {
        int h = tid / 48, jj = tid % 48;
        float val = 0.f;
        if (jj < 40) {
            int cj = h*40 + jj;
            val = b1[jj] + cpart[cj*3] + cpart[cj*3+1] + cpart[cj*3+2];
        }
        cs[(size_t)(br*NB + b)*96 + tid] = val;
    }
}

// ---- main v9: 256 threads per (b,br); 8 iters x TWO INDEPENDENT row tiles.
//  r8 evidence: weights reg-vs-LDS neutral, nothing saturated, ~80% of wave time
//  is serial-chain stall (unroll-1 forbids cross-iteration overlap).  Fix: two
//  full chains per loop body with SEPARATE tn buffers (manual, not unroll-2, so
//  ds_write(b) can't alias ds_read(a) and re-serialize).  Shared bias/Cs/w2/Cfrag
//  loads serve both tiles.  Bfrag stays in regs (AGPR); Cfrag in LDS (free).
__global__ __launch_bounds__(256, 1) void main_kernel(
    const float* __restrict__ xloc, const float* __restrict__ xnon,
    const float* __restrict__ blx,  const float* __restrict__ alx,
    const float* __restrict__ bnx,  const float* __restrict__ anx,
    const float* __restrict__ la1,  const float* __restrict__ lw2, const float* __restrict__ lb2,
    const float* __restrict__ na1,  const float* __restrict__ nw2, const float* __restrict__ nb2,
    const u32* __restrict__ wtf, const u32* __restrict__ weff, const float* __restrict__ cs,
    float* __restrict__ out)
{
    __shared__ u16   tn[4*2*16*136]; // per-wave TWO 16x128 bf16 tiles (34816 B)
    __shared__ u32   cf_sm[3072];    // 12 frags x 64 lanes x 16B = 12 KB
    __shared__ float bias_sm[128];
    __shared__ float cs_sm[96];
    __shared__ float w2_sm[48];
    // total ~48.2 KB; grid 512 -> 2 blocks/CU resident, no tail

    const int tid  = threadIdx.x;
    const int b    = blockIdx.x;
    const int br   = blockIdx.y;
    const int w    = tid >> 6;
    const int lane = tid & 63;
    const int q    = lane >> 4;
    const int lm   = lane & 15;

    const float* xg   = br ? xnon : xloc;
    const float* bias = br ? bnx  : blx;
    const float  am1  = (br ? anx[0] : alx[0]) - 1.f;   // prelu: v + (a-1)*min(v,0)
    const float  a1m1 = (br ? na1[0] : la1[0]) - 1.f;
    const float  b2v  = br ? nb2[0] : lb2[0];
    const float* w2   = br ? nw2  : lw2;

    // ---- stage Cfrag + small tables into LDS ----
    {
        const uint4* csrc = (const uint4*)weff + (size_t)(br*NB + b)*768;
        uint4* cdst = (uint4*)cf_sm;
        #pragma unroll
        for (int k = 0; k < 3; ++k) cdst[k*256 + tid] = csrc[k*256 + tid];
    }
    if (tid < 128) bias_sm[tid] = bias[tid];
    if (tid < 96)  cs_sm[tid]   = cs[(size_t)(br*NB + b)*96 + tid];
    if (tid < 48)  w2_sm[tid]   = (tid < 40) ? w2[tid] : 0.f;

    // ---- Bfrag persistent in registers (AGPR via unified file; r8-verified) ----
    const bf8_t* wtfv = (const bf8_t*)wtf;
    bf8_t Bfrag[8][2];
    #pragma unroll
    for (int n = 0; n < 8; ++n)
        #pragma unroll
        for (int ks = 0; ks < 2; ++ks)
            Bfrag[n][ks] = wtfv[(br*16 + n*2 + ks)*64 + lane];

    __syncthreads();

    u16* twa = &tn[w*4352];
    u16* twb = twa + 2176;
    const f4_t zero4 = {0.f, 0.f, 0.f, 0.f};
    float outp[8][4];
    #pragma unroll
    for (int c = 0; c < 8; ++c)
        #pragma unroll
        for (int r = 0; r < 4; ++r) outp[c][r] = 0.f;

    const float* xb = &xg[(size_t)b*NS*64];
    // iter it: tile A = it*8 + w, tile B = it*8 + 4 + w (it = 0..7 covers all 64)

    float4 pa0, pa1, pa2, pa3, pb0, pb1, pb2, pb3;
    {
        const float* xra = xb + (size_t)(w*16 + lm)*64;
        pa0 = *(const float4*)(xra + q*8);
        pa1 = *(const float4*)(xra + q*8 + 4);
        pa2 = *(const float4*)(xra + 32 + q*8);
        pa3 = *(const float4*)(xra + 32 + q*8 + 4);
        const float* xrb = xb + (size_t)((4 + w)*16 + lm)*64;
        pb0 = *(const float4*)(xrb + q*8);
        pb1 = *(const float4*)(xrb + q*8 + 4);
        pb2 = *(const float4*)(xrb + 32 + q*8);
        pb3 = *(const float4*)(xrb + 32 + q*8 + 4);
    }

    #pragma unroll 1
    for (int it = 0; it < 8; ++it) {
        // opaque zero: blocks LICM from hoisting loop-invariant LDS reads
        u32 zoff = 0;
        asm volatile("" : "+v"(zoff));
        const u32*   cfp = cf_sm + zoff;
        const float* bip = bias_sm + zoff;
        const float* cvp = cs_sm + zoff;
        const float* w2p = w2_sm + zoff;

        float4 ca0 = pa0, ca1 = pa1, ca2 = pa2, ca3 = pa3;
        float4 cb0 = pb0, cb1 = pb1, cb2 = pb2, cb3 = pb3;
        if (it < 7) {
            const float* xra = xb + (size_t)(((it+1)*8 + w)*16 + lm)*64;
            pa0 = *(const float4*)(xra + q*8);
            pa1 = *(const float4*)(xra + q*8 + 4);
            pa2 = *(const float4*)(xra + 32 + q*8);
            pa3 = *(const float4*)(xra + 32 + q*8 + 4);
            const float* xrb = xb + (size_t)(((it+1)*8 + 4 + w)*16 + lm)*64;
            pb0 = *(const float4*)(xrb + q*8);
            pb1 = *(const float4*)(xrb + q*8 + 4);
            pb2 = *(const float4*)(xrb + 32 + q*8);
            pb3 = *(const float4*)(xrb + 32 + q*8 + 4);
        }

        union { u32 u[4]; bf8_t v; } Aa0, Aa1, Ab0, Ab1;
        Aa0.u[0] = pack_trunc(ca0.x, ca0.y); Aa0.u[1] = pack_trunc(ca0.z, ca0.w);
        Aa0.u[2] = pack_trunc(ca1.x, ca1.y); Aa0.u[3] = pack_trunc(ca1.z, ca1.w);
        Aa1.u[0] = pack_trunc(ca2.x, ca2.y); Aa1.u[1] = pack_trunc(ca2.z, ca2.w);
        Aa1.u[2] = pack_trunc(ca3.x, ca3.y); Aa1.u[3] = pack_trunc(ca3.z, ca3.w);
        Ab0.u[0] = pack_trunc(cb0.x, cb0.y); Ab0.u[1] = pack_trunc(cb0.z, cb0.w);
        Ab0.u[2] = pack_trunc(cb1.x, cb1.y); Ab0.u[3] = pack_trunc(cb1.z, cb1.w);
        Ab1.u[0] = pack_trunc(cb2.x, cb2.y); Ab1.u[1] = pack_trunc(cb2.z, cb2.w);
        Ab1.u[2] = pack_trunc(cb3.x, cb3.y); Ab1.u[3] = pack_trunc(cb3.z, cb3.w);

        // ---- Phase B (both tiles, shared bias): t^T = W^T @ x^T ----
        float tva[8][4], tvb[8][4];
        float sa0 = 0.f, sa1 = 0.f, sa2 = 0.f, sa3 = 0.f;
        float sb0 = 0.f, sb1 = 0.f, sb2 = 0.f, sb3 = 0.f;
        #pragma unroll
        for (int c = 0; c < 8; ++c) {
            f4_t bi = *(const f4_t*)&bip[c*16 + q*4];
            f4_t qa = __builtin_amdgcn_mfma_f32_16x16x32_bf16(Bfrag[c][0], Aa0.v, bi, 0, 0, 0);
            qa      = __builtin_amdgcn_mfma_f32_16x16x32_bf16(Bfrag[c][1], Aa1.v, qa, 0, 0, 0);
            f4_t qb = __builtin_amdgcn_mfma_f32_16x16x32_bf16(Bfrag[c][0], Ab0.v, bi, 0, 0, 0);
            qb      = __builtin_amdgcn_mfma_f32_16x16x32_bf16(Bfrag[c][1], Ab1.v, qb, 0, 0, 0);
            float a0 = qa[0]; a0 = fmaf(fminf(a0, 0.f), am1, a0); tva[c][0] = a0; sa0 = fmaf(a0, a0, sa0);
            float a1 = qa[1]; a1 = fmaf(fminf(a1, 0.f), am1, a1); tva[c][1] = a1; sa1 = fmaf(a1, a1, sa1);
            float a2 = qa[2]; a2 = fmaf(fminf(a2, 0.f), am1, a2); tva[c][2] = a2; sa2 = fmaf(a2, a2, sa2);
            float a3 = qa[3]; a3 = fmaf(fminf(a3, 0.f), am1, a3); tva[c][3] = a3; sa3 = fmaf(a3, a3, sa3);
            float b0 = qb[0]; b0 = fmaf(fminf(b0, 0.f), am1, b0); tvb[c][0] = b0; sb0 = fmaf(b0, b0, sb0);
            float b1 = qb[1]; b1 = fmaf(fminf(b1, 0.f), am1, b1); tvb[c][1] = b1; sb1 = fmaf(b1, b1, sb1);
            float b2 = qb[2]; b2 = fmaf(fminf(b2, 0.f), am1, b2); tvb[c][2] = b2; sb2 = fmaf(b2, b2, sb2);
            float b3 = qb[3]; b3 = fmaf(fminf(b3, 0.f), am1, b3); tvb[c][3] = b3; sb3 = fmaf(b3, b3, sb3);
        }

        // unnormalized t -> per-tile LDS buffers (issued before the shuffle chain
        // so the lgkmcnt drain overlaps the reductions below)
        #pragma unroll
        for (int c = 0; c < 8; ++c) {
            *(uint2*)&twa[lm*136 + c*16 + q*4] =
                make_uint2(pack_trunc(tva[c][0], tva[c][1]), pack_trunc(tva[c][2], tva[c][3]));
            *(uint2*)&twb[lm*136 + c*16 + q*4] =
                make_uint2(pack_trunc(tvb[c][0], tvb[c][1]), pack_trunc(tvb[c][2], tvb[c][3]));
        }

        float ssqa = (sa0 + sa1) + (sa2 + sa3);
        ssqa += __shfl_xor(ssqa, 16);
        ssqa += __shfl_xor(ssqa, 32);
        const float rinva = rsqrtf(fmaxf(ssqa, 1e-24f));
        float ssqb = (sb0 + sb1) + (sb2 + sb3);
        ssqb += __shfl_xor(ssqb, 16);
        ssqb += __shfl_xor(ssqb, 32);
        const float rinvb = rsqrtf(fmaxf(ssqb, 1e-24f));

        // ---- Phase C (both tiles, shared Cfrag/Cs/w2 loads) ----
        float pwa[2], pwb[2];
        #pragma unroll
        for (int h = 0; h < 2; ++h) {
            bf8_t aca0 = *(const bf8_t*)&twa[lm*136 + h*64 + q*8];
            bf8_t aca1 = *(const bf8_t*)&twa[lm*136 + h*64 + 32 + q*8];
            bf8_t acb0 = *(const bf8_t*)&twb[lm*136 + h*64 + q*8];
            bf8_t acb1 = *(const bf8_t*)&twb[lm*136 + h*64 + 32 + q*8];
            float ppa[3], ppb[3];
            #pragma unroll
            for (int nj = 0; nj < 3; ++nj) {
                f4_t cv = *(const f4_t*)&cvp[h*48 + nj*16 + q*4];
                f4_t wv = *(const f4_t*)&w2p[nj*16 + q*4];
                bf8_t cf0 = *(const bf8_t*)&cfp[((h*6 + nj*2 + 0)*64 + lane)*4];
                bf8_t cf1 = *(const bf8_t*)&cfp[((h*6 + nj*2 + 1)*64 + lane)*4];
                f4_t qa = __builtin_amdgcn_mfma_f32_16x16x32_bf16(cf0, aca0, zero4, 0, 0, 0);
                qa      = __builtin_amdgcn_mfma_f32_16x16x32_bf16(cf1, aca1, qa,    0, 0, 0);
                f4_t qb = __builtin_amdgcn_mfma_f32_16x16x32_bf16(cf0, acb0, zero4, 0, 0, 0);
                qb      = __builtin_amdgcn_mfma_f32_16x16x32_bf16(cf1, acb1, qb,    0, 0, 0);
                float pla = 0.f, plb = 0.f;
                #pragma unroll
                for (int r = 0; r < 4; ++r) {
                    float va = fmaf(qa[r], rinva, cv[r]);
                    va = fmaf(fminf(va, 0.f), a1m1, va);
                    pla = fmaf(va, wv[r], pla);
                    float vb = fmaf(qb[r], rinvb, cv[r]);
                    vb = fmaf(fminf(vb, 0.f), a1m1, vb);
                    plb = fmaf(vb, wv[r], plb);
                }
                ppa[nj] = pla; ppb[nj] = plb;
            }
            float p_a = (ppa[0] + ppa[1]) + ppa[2];
            p_a += __shfl_xor(p_a, 16);
            p_a += __shfl_xor(p_a, 32);
            pwa[h] = (p_a + b2v) * rinva;
            float p_b = (ppb[0] + ppb[1]) + ppb[2];
            p_b += __shfl_xor(p_b, 16);
            p_b += __shfl_xor(p_b, 32);
            pwb[h] = (p_b + b2v) * rinvb;
        }

        // ---- Phase D (registers): outp[col] += t[lm][col] * pw ----
        #pragma unroll
        for (int c = 0; c < 8; ++c)
            #pragma unroll
            for (int r = 0; r < 4; ++r) {
                outp[c][r] = fmaf(tva[c][r], pwa[c >> 2], outp[c][r]);
                outp[c][r] = fmaf(tvb[c][r], pwb[c >> 2], outp[c][r]);
            }
    }

    // reduce over rows (lm lanes), once
    #pragma unroll
    for (int c = 0; c < 8; ++c)
        #pragma unroll
        for (int r = 0; r < 4; ++r) {
            float v = outp[c][r];
            v += __shfl_xor(v, 1);
            v += __shfl_xor(v, 2);
            v += __shfl_xor(v, 4);
            v += __shfl_xor(v, 8);
            outp[c][r] = v;
        }

    __syncthreads();                 // all waves done with tn -> reuse as red
    float* red = (float*)tn;         // 4*128 floats = 2 KB, aliases tn
    if (lm == 0) {
        #pragma unroll
        for (int c = 0; c < 8; ++c) {
            f4_t v = { outp[c][0], outp[c][1], outp[c][2], outp[c][3] };
            *(f4_t*)&red[w*128 + c*16 + q*4] = v;
        }
    }
    __syncthreads();
    if (tid < 128) {
        float s = red[tid] + red[128 + tid] + red[256 + tid] + red[384 + tid];
        out[((size_t)br*NB + b)*128 + tid] = s;
    }
}

extern "C" void kernel_launch(void* const* d_in, const int* in_sizes, int n_in,
                              void* d_out, int out_size, void* d_ws, size_t ws_size,
                              hipStream_t stream)
{
    const float* xl  = (const float*)d_in[0];
    const float* xn  = (const float*)d_in[1];
    const float* y   = (const float*)d_in[2];
    const float* uid = (const float*)d_in[3];
    const float* ose = (const float*)d_in[4];
    const float* zp  = (const float*)d_in[5];
    const float* wty = (const float*)d_in[6];
    const float* bty = (const float*)d_in[7];
    const float* aty = (const float*)d_in[8];
    const float* wlx = (const float*)d_in[9];
    const float* blx = (const float*)d_in[10];
    const float* alx = (const float*)d_in[11];
    const float* wnx = (const float*)d_in[12];
    const float* bnx = (const float*)d_in[13];
    const float* anx = (const float*)d_in[14];
    const float* lw1 = (const float*)d_in[15];
    const float* lb1 = (const float*)d_in[16];
    const float* la1 = (const float*)d_in[17];
    const float* lw2 = (const float*)d_in[18];
    const float* lb2 = (const float*)d_in[19];
    const float* nw1 = (const float*)d_in[20];
    const float* nb1 = (const float*)d_in[21];
    const float* na1 = (const float*)d_in[22];
    const float* nw2 = (const float*)d_in[23];
    const float* nb2 = (const float*)d_in[24];

    // ws layout (16B-aligned segments)
    u32*   wtf  = (u32*)d_ws;                               // 2048*16B = 32 KB
    u32*   weff = (u32*)((char*)d_ws + 32768);              // 512*12*64*16B = 6 MB
    float* cs   = (float*)((char*)d_ws + 32768 + 6291456);  // 512*96*4 = 192 KB

    prep_kernel<<<dim3(520), dim3(256), 0, stream>>>(
        y, wty, bty, aty, uid, ose, zp, wlx, wnx, lw1, lb1, nw1, nb1, wtf, weff, cs);
    main_kernel<<<dim3(NB, 2), dim3(256), 0, stream>>>(
        xl, xn, blx, alx, bnx, anx,
        la1, lw2, lb2, na1, nw2, nb2,
        wtf, weff, cs, (float*)d_out);
}